// Round 1
// baseline (209.116 us; speedup 1.0000x reference)
//
#include <hip/hip_runtime.h>
#include <stdint.h>

// Binary conv via bit-pack + XNOR popcount.
// A: [32,64,112,112] f32, W: [64,64,3,3] f32 (flat), out: [32,64,112,112] f32.
// sign(x) encoded as bit = signbit(x)  (x==0 -> treated +1; error <=1 << 2.4 thr)
// dot over 64 channels = 64 - 2*popc(a ^ w); padding via mask words.

#define NN 32
#define CC 64
#define HH 112
#define WW 112
#define OO 64
#define HW (HH*WW)       // 12544
#define NHW (NN*HW)      // 401408

#define PACK_BLOCK 256
#define PIXG 4
#define PACK_A_THREADS (NHW/PIXG)               // 100352
#define PACK_A_BLOCKS (PACK_A_THREADS/PACK_BLOCK) // 392

#define CONV_BLOCK 256
#define CONV_BLOCKS (NHW/CONV_BLOCK)            // 1568

__global__ __launch_bounds__(PACK_BLOCK)
void pack_kernel(const float* __restrict__ act, const float* __restrict__ wgt,
                 uint64_t* __restrict__ ap, uint64_t* __restrict__ wp) {
    int b = blockIdx.x;
    if (b == PACK_A_BLOCKS) {
        // ---- pack weights: wp[o*9+k] bit i = signbit(W[o][i][kh][kw]) ----
        for (int t = threadIdx.x; t < OO * 9; t += PACK_BLOCK) {
            int o = t / 9, k = t - o * 9;
            uint32_t lo = 0, hi = 0;
            #pragma unroll
            for (int i = 0; i < 64; ++i) {
                uint32_t s = __float_as_uint(wgt[(o * 64 + i) * 9 + k]) >> 31;
                if (i < 32) lo |= s << i;
                else        hi |= s << (i - 32);
            }
            wp[t] = ((uint64_t)hi << 32) | lo;
        }
        return;
    }
    // ---- pack activations: 4 pixels (float4 across w) per thread ----
    int t = b * PACK_BLOCK + threadIdx.x;        // float4-group id over N*HW/4
    int n = t / (HW / 4);
    int rem4 = t - n * (HW / 4);
    const float4* base = (const float4*)act + (size_t)n * CC * (HW / 4) + rem4;
    uint32_t lo[4] = {0, 0, 0, 0}, hi[4] = {0, 0, 0, 0};
    #pragma unroll
    for (int c = 0; c < 64; ++c) {
        float4 v = base[(size_t)c * (HW / 4)];   // coalesced: 64 lanes x 16B
        uint32_t s0 = __float_as_uint(v.x) >> 31;
        uint32_t s1 = __float_as_uint(v.y) >> 31;
        uint32_t s2 = __float_as_uint(v.z) >> 31;
        uint32_t s3 = __float_as_uint(v.w) >> 31;
        if (c < 32) {
            lo[0] |= s0 << c; lo[1] |= s1 << c; lo[2] |= s2 << c; lo[3] |= s3 << c;
        } else {
            int cc = c - 32;
            hi[0] |= s0 << cc; hi[1] |= s1 << cc; hi[2] |= s2 << cc; hi[3] |= s3 << cc;
        }
    }
    ulonglong2 w01, w23;
    w01.x = ((uint64_t)hi[0] << 32) | lo[0];
    w01.y = ((uint64_t)hi[1] << 32) | lo[1];
    w23.x = ((uint64_t)hi[2] << 32) | lo[2];
    w23.y = ((uint64_t)hi[3] << 32) | lo[3];
    ulonglong2* dst = (ulonglong2*)(ap + (size_t)t * 4);
    dst[0] = w01;
    dst[1] = w23;
}

__global__ __launch_bounds__(CONV_BLOCK)
void conv_kernel(const uint64_t* __restrict__ ap, const uint64_t* __restrict__ wp,
                 float* __restrict__ out) {
    int idx = blockIdx.x * CONV_BLOCK + threadIdx.x;   // one output pixel (all 64 o)
    int n = idx / HW;
    int rem = idx - n * HW;
    int h = rem / WW;
    int w = rem - h * WW;
    const uint64_t* apn = ap + (size_t)n * HW;

    uint64_t a[9], m[9];
    int nvalid = 0;
    #pragma unroll
    for (int kh = 0; kh < 3; ++kh) {
        int hh = h + kh - 1;
        bool hv = (unsigned)hh < (unsigned)HH;
        #pragma unroll
        for (int kw = 0; kw < 3; ++kw) {
            int ww2 = w + kw - 1;
            bool wv = (unsigned)ww2 < (unsigned)WW;
            bool v = hv && wv;
            int k = kh * 3 + kw;
            int ch = hv ? hh : h;            // clamped (safe) address
            int cw = wv ? ww2 : w;
            a[k] = apn[ch * WW + cw];
            m[k] = v ? ~0ull : 0ull;
            nvalid += v ? 1 : 0;
        }
    }
    int base = 64 * nvalid;
    float* op = out + (size_t)n * (OO * HW) + rem;
    for (int o = 0; o < OO; ++o) {
        const uint64_t* wk = wp + o * 9;     // uniform index -> scalar loads
        int s = 0;
        #pragma unroll
        for (int k = 0; k < 9; ++k)
            s += __popcll((a[k] ^ wk[k]) & m[k]);
        op[(size_t)o * HW] = (float)(base - 2 * s);
    }
}

extern "C" void kernel_launch(void* const* d_in, const int* in_sizes, int n_in,
                              void* d_out, int out_size, void* d_ws, size_t ws_size,
                              hipStream_t stream) {
    const float* act = (const float*)d_in[0];
    const float* wgt = (const float*)d_in[1];
    float* out = (float*)d_out;

    uint64_t* wp = (uint64_t*)d_ws;          // 576 words (rounded to 1024)
    uint64_t* ap = wp + 1024;                // 401408 words (~3.2 MB)

    pack_kernel<<<PACK_A_BLOCKS + 1, PACK_BLOCK, 0, stream>>>(act, wgt, ap, wp);
    conv_kernel<<<CONV_BLOCKS, CONV_BLOCK, 0, stream>>>(ap, wp, out);
}